// Round 11
// baseline (42.423 us; speedup 1.0000x reference)
//
#include <hip/hip_runtime.h>
#include <hip/hip_bf16.h>

#define NP     64     // partitions
#define D_IN   1024
#define RANK   64
#define D_OUT  1024
#define NTOK   4096
#define TM     64     // tokens per tile
#define BK     64     // K chunk for h step
#define MT     128    // max tiles (worst case 127)
#define KS     8      // K-split for h_kernel
#define KW     (D_IN / KS)   // 128
#define OW     128    // D_OUT cols per o-block
#define LDSTR  72     // LDS row stride in bf16 elems (144B, 16B-aligned)

typedef __bf16 bf16x8 __attribute__((ext_vector_type(8)));
typedef float  f32x4  __attribute__((ext_vector_type(4)));

__device__ __forceinline__ unsigned short f2bf(float f) {
    unsigned u = __builtin_bit_cast(unsigned, f);
    u += 0x7FFFu + ((u >> 16) & 1u);   // round-to-nearest-even
    return (unsigned short)(u >> 16);
}
__device__ __forceinline__ float bf2f(unsigned short s) {
    unsigned u = (unsigned)s << 16;
    return __builtin_bit_cast(float, u);
}
__device__ __forceinline__ bf16x8 pack8(float4 a, float4 b) {
    union { bf16x8 v; unsigned short s[8]; } r;
    r.s[0] = f2bf(a.x); r.s[1] = f2bf(a.y); r.s[2] = f2bf(a.z); r.s[3] = f2bf(a.w);
    r.s[4] = f2bf(b.x); r.s[5] = f2bf(b.y); r.s[6] = f2bf(b.z); r.s[7] = f2bf(b.w);
    return r.v;
}

// XOR-swizzled LDS index: tile [outer][LDSTR] of ushort, inner dim permuted in
// 8-elem blocks by (outer>>3)&7 — bank-conflict-free writes, contiguous b128 reads.
__device__ __forceinline__ int swz_idx(int outer, int inner) {
    int blk = (inner >> 3) ^ ((outer >> 3) & 7);
    return outer * LDSTR + blk * 8 + (inner & 7);
}

// XCD-aware decode: all 8 ks-producers and 8 oc-consumers of a tile satisfy
// b%8 == (tile>>1)&7 -> same XCD's L2 holds that tile's Hpart.
__device__ __forceinline__ void decode_xcd(int b, int& tile, int& slice) {
    int g = b & 7;
    int l = b >> 3;
    slice = l >> 4;                         // ks or oc chunk, 0..7
    int m = l & 15;
    tile = (((m >> 1) << 3) | g) * 2 + (m & 1);
}

// ---------------------------------------------------------------------------
// Kernel 1: partial H (bf16) with IN-BLOCK bucketing (no bucket dispatch).
// grid = MT*KS = 1024; block (tile,ks):
//   1) redundantly derive tile->(p,len) + this tile's token ids from pids
//      (histogram + shfl prefix + ordered ballot compaction);
//   2) Hpart[ks][tile] (64x64) = Xtile[:, ks*KW..] @ U[p][slice];
//   3) ks==0 block publishes toks + tile record to meta for o_kernel.
// meta (ints): [0]=n_tiles; records int4 at [16+4t]=(p, t*64, len, 0);
//              bucket at [1024 + tile*64 ..)
// ---------------------------------------------------------------------------
__global__ __launch_bounds__(256, 4) void h_kernel(
    const float* __restrict__ x, const int* __restrict__ pids,
    const float* __restrict__ U, int* __restrict__ meta,
    unsigned short* __restrict__ Hpart)
{
    __shared__ __align__(16) unsigned short Us[2][RANK * LDSTR];
    __shared__ int counts[NP];
    __shared__ int tpref[NP];      // exclusive tile prefix
    __shared__ int ntps[NP];       // tiles per partition
    __shared__ int toks[TM];
    __shared__ int wtot[4];
    __shared__ int nt_sm, pidx_sm;

    int tid  = threadIdx.x;
    int lane = tid & 63;
    int w    = tid >> 6;
    int l15  = lane & 15;
    int l4   = lane >> 4;

    int tile, ks;
    decode_xcd(blockIdx.x, tile, ks);

    // ---- load all pids into regs (16 per thread, order = (c, tid, j)) ----
    int4 pv[4];
#pragma unroll
    for (int c = 0; c < 4; ++c)
        pv[c] = reinterpret_cast<const int4*>(pids)[c * 256 + tid];

    if (tid < NP) { counts[tid] = 0; }
    if (tid < TM) { toks[tid] = -1; }
    __syncthreads();

    // ---- histogram ----
#pragma unroll
    for (int c = 0; c < 4; ++c) {
        atomicAdd(&counts[pv[c].x & (NP - 1)], 1);
        atomicAdd(&counts[pv[c].y & (NP - 1)], 1);
        atomicAdd(&counts[pv[c].z & (NP - 1)], 1);
        atomicAdd(&counts[pv[c].w & (NP - 1)], 1);
    }
    __syncthreads();

    // ---- tile prefix over partitions (wave 0, lanes 0..63) ----
    if (tid < 64) {
        int c = counts[tid];
        int ntp = (c + TM - 1) >> 6;
        int st = ntp;
        for (int d = 1; d < 64; d <<= 1) {
            int v = __shfl_up(st, d);
            if (tid >= d) st += v;
        }
        tpref[tid] = st - ntp;
        ntps[tid]  = ntp;
        if (tid == 63) nt_sm = st;
    }
    __syncthreads();

    int nt = nt_sm;
    if (blockIdx.x == 0 && tid == 0) meta[0] = nt;
    if (tile >= nt) return;

    // ---- find partition p owning this tile ----
    if (tid < 64) {
        if (tpref[tid] <= tile && tile < tpref[tid] + ntps[tid]) pidx_sm = tid;
    }
    __syncthreads();
    int p = pidx_sm;
    int t_local = tile - tpref[p];
    int lo  = t_local * TM;
    int len = counts[p] - lo; if (len > TM) len = TM;

    // ---- ordered compaction: ranks [lo, lo+64) of matches -> toks ----
    {
        int running = 0;
        for (int c = 0; c < 4 && running < lo + TM; ++c) {
            int4 pp = pv[c];
            int m0 = ((pp.x & (NP - 1)) == p);
            int m1 = ((pp.y & (NP - 1)) == p);
            int m2 = ((pp.z & (NP - 1)) == p);
            int m3 = ((pp.w & (NP - 1)) == p);
            int mycnt = m0 + m1 + m2 + m3;
            int s = mycnt;
            for (int d = 1; d < 64; d <<= 1) {
                int v = __shfl_up(s, d);
                if (lane >= d) s += v;
            }
            if (lane == 63) wtot[w] = s;
            __syncthreads();
            int wbase = running;
            for (int j = 0; j < 4; ++j) if (j < w) wbase += wtot[j];
            int r = wbase + s - mycnt;           // exclusive rank of my first match
            int g = (c * 1024) + tid * 4;        // first token id in my int4
            if (m0) { int rel = r - lo; if (rel >= 0 && rel < TM) toks[rel] = g + 0; ++r; }
            if (m1) { int rel = r - lo; if (rel >= 0 && rel < TM) toks[rel] = g + 1; ++r; }
            if (m2) { int rel = r - lo; if (rel >= 0 && rel < TM) toks[rel] = g + 2; ++r; }
            if (m3) { int rel = r - lo; if (rel >= 0 && rel < TM) toks[rel] = g + 3; ++r; }
            int tot = wtot[0] + wtot[1] + wtot[2] + wtot[3];
            __syncthreads();
            running += tot;
        }
    }
    __syncthreads();

    // ---- ks==0 block publishes toks + record for o_kernel ----
    if (ks == 0) {
        if (tid < TM) meta[1024 + tile * TM + tid] = toks[tid];
        if (tid == 0) {
            int4 rec = {p, tile * TM, len, 0};
            *reinterpret_cast<int4*>(meta + 16 + 4 * tile) = rec;
        }
    }

    // ================== GEMM: identical to proven r10 h ==================
    int myrow = w * 16 + l15;
    int t = toks[myrow];
    bool valid = (t >= 0);
    const float* xrow = x + (size_t)(valid ? t : 0) * D_IN;
    const float* Up = U + (size_t)p * D_IN * RANK;

    int kbeg = ks * KW;
    int kk = tid >> 2;            // 0..63 staging k-row
    int q  = (tid & 3) * 16;      // r quarter

    float4 z{0,0,0,0};
    float4 c0a=z,c0b=z,c0c=z,c0d=z,c1a=z,c1b=z,c1c=z,c1d=z;
    if (valid) {
        const float* xp = xrow + kbeg + l4 * 8;
        c0a = *reinterpret_cast<const float4*>(xp);
        c0b = *reinterpret_cast<const float4*>(xp + 4);
        c0c = *reinterpret_cast<const float4*>(xp + 32);
        c0d = *reinterpret_cast<const float4*>(xp + 36);
        c1a = *reinterpret_cast<const float4*>(xp + 64);
        c1b = *reinterpret_cast<const float4*>(xp + 68);
        c1c = *reinterpret_cast<const float4*>(xp + 96);
        c1d = *reinterpret_cast<const float4*>(xp + 100);
    }

    f32x4 acc[4] = {};

    // ---- stage chunk 0 -> Us[0] (transposed, swizzled) ----
    {
        const float* up = Up + (size_t)(kbeg + kk) * RANK + q;
#pragma unroll
        for (int i = 0; i < 4; ++i) {
            float4 v = *reinterpret_cast<const float4*>(up + i * 4);
            int r = q + i * 4;
            Us[0][swz_idx(r + 0, kk)] = f2bf(v.x);
            Us[0][swz_idx(r + 1, kk)] = f2bf(v.y);
            Us[0][swz_idx(r + 2, kk)] = f2bf(v.z);
            Us[0][swz_idx(r + 3, kk)] = f2bf(v.w);
        }
    }
    __syncthreads();

    // ---- issue chunk-1 U loads into regs (latency hides under mfma0) ----
    float4 u10, u11, u12, u13;
    {
        const float* up = Up + (size_t)(kbeg + BK + kk) * RANK + q;
        u10 = *reinterpret_cast<const float4*>(up);
        u11 = *reinterpret_cast<const float4*>(up + 4);
        u12 = *reinterpret_cast<const float4*>(up + 8);
        u13 = *reinterpret_cast<const float4*>(up + 12);
    }

    // ---- mfma chunk 0 ----
    {
        bf16x8 a0 = pack8(c0a, c0b);
        bf16x8 a1 = pack8(c0c, c0d);
#pragma unroll
        for (int k2 = 0; k2 < 2; ++k2) {
            int kof = k2 * 32 + l4 * 8;
            bf16x8 a = k2 ? a1 : a0;
#pragma unroll
            for (int ni = 0; ni < 4; ++ni) {
                bf16x8 b = *reinterpret_cast<const bf16x8*>(&Us[0][swz_idx(ni * 16 + l15, kof)]);
                acc[ni] = __builtin_amdgcn_mfma_f32_16x16x32_bf16(a, b, acc[ni], 0, 0, 0);
            }
        }
    }

    // ---- convert + write chunk 1 -> Us[1] ----
    {
        float4 vv[4] = {u10, u11, u12, u13};
#pragma unroll
        for (int i = 0; i < 4; ++i) {
            int r = q + i * 4;
            Us[1][swz_idx(r + 0, kk)] = f2bf(vv[i].x);
            Us[1][swz_idx(r + 1, kk)] = f2bf(vv[i].y);
            Us[1][swz_idx(r + 2, kk)] = f2bf(vv[i].z);
            Us[1][swz_idx(r + 3, kk)] = f2bf(vv[i].w);
        }
    }
    __syncthreads();

    // ---- mfma chunk 1 ----
    {
        bf16x8 a0 = pack8(c1a, c1b);
        bf16x8 a1 = pack8(c1c, c1d);
#pragma unroll
        for (int k2 = 0; k2 < 2; ++k2) {
            int kof = k2 * 32 + l4 * 8;
            bf16x8 a = k2 ? a1 : a0;
#pragma unroll
            for (int ni = 0; ni < 4; ++ni) {
                bf16x8 b = *reinterpret_cast<const bf16x8*>(&Us[1][swz_idx(ni * 16 + l15, kof)]);
                acc[ni] = __builtin_amdgcn_mfma_f32_16x16x32_bf16(a, b, acc[ni], 0, 0, 0);
            }
        }
    }

    // write bf16 partial H; C/D layout: col=lane&15, row=(lane>>4)*4+reg
    unsigned short* hp = Hpart + ((size_t)ks * MT + tile) * (TM * RANK);
#pragma unroll
    for (int ni = 0; ni < 4; ++ni)
#pragma unroll
        for (int j = 0; j < 4; ++j) {
            int row = w * 16 + l4 * 4 + j;
            int col = ni * 16 + l15;
            hp[row * RANK + col] = f2bf(acc[ni][j]);
        }
}

// ---------------------------------------------------------------------------
// Kernel 2: O = H @ V[p] + bias for one (tile, 128-col chunk). grid = MT*8.
// Split-K reduction fused in registers (Hpart is XCD-local L2).
// V global loads + token-id loads issued first; reduction VALU overlaps.
// ---------------------------------------------------------------------------
__global__ __launch_bounds__(256, 4) void o_kernel(
    const float* __restrict__ V, const float* __restrict__ bias,
    const int* __restrict__ meta, const unsigned short* __restrict__ Hpart,
    float* __restrict__ out)
{
    __shared__ __align__(16) unsigned short Vs[OW * LDSTR];

    int tile, ocs;
    decode_xcd(blockIdx.x, tile, ocs);
    int oc = ocs * OW;
    int nt = meta[0];
    if (tile >= nt) return;
    int4 ti = *reinterpret_cast<const int4*>(meta + 16 + 4 * tile);
    int p = ti.x, off = ti.y, len = ti.z;

    int tid  = threadIdx.x;
    int lane = tid & 63;
    int w    = tid >> 6;
    int l15  = lane & 15;
    int l4   = lane >> 4;

    // ---- issue V global loads into regs first ----
    const float* Vp = V + (size_t)p * RANK * D_OUT;
    int o4 = (tid & 31) * 4;
    int rb = tid >> 5;          // 0..7
    float4 vv[8];
#pragma unroll
    for (int pass = 0; pass < 8; ++pass) {
        int r = pass * 8 + rb;
        vv[pass] = *reinterpret_cast<const float4*>(&Vp[(size_t)r * D_OUT + oc + o4]);
    }

    // ---- token ids issued early too (consumed at the store) ----
    const int* bucket = meta + 1024;
    int r0 = w * 16 + l4 * 4;
    int t0 = bucket[off + r0 + 0], t1 = bucket[off + r0 + 1];
    int t2 = bucket[off + r0 + 2], t3 = bucket[off + r0 + 3];

    // ---- fused split-K reduction -> A-frags (overlaps V-load latency) ----
    size_t hoff = (size_t)tile * (TM * RANK) + (w * 16 + l15) * RANK + l4 * 8;
    float s0[8] = {}, s1[8] = {};
#pragma unroll
    for (int k = 0; k < KS; ++k) {
        const unsigned short* pp = Hpart + (size_t)k * (MT * TM * RANK) + hoff;
        union { int4 i4; unsigned short u[8]; } va, vb;
        va.i4 = *reinterpret_cast<const int4*>(pp);
        vb.i4 = *reinterpret_cast<const int4*>(pp + 32);
#pragma unroll
        for (int j = 0; j < 8; ++j) { s0[j] += bf2f(va.u[j]); s1[j] += bf2f(vb.u[j]); }
    }
    union { bf16x8 v; unsigned short u[8]; } fa0, fa1;
#pragma unroll
    for (int j = 0; j < 8; ++j) { fa0.u[j] = f2bf(s0[j]); fa1.u[j] = f2bf(s1[j]); }

    // ---- write V to LDS transposed (swizzled): Vs[o][r] = V[p][r][oc+o] ----
#pragma unroll
    for (int pass = 0; pass < 8; ++pass) {
        int r = pass * 8 + rb;
        Vs[swz_idx(o4 + 0, r)] = f2bf(vv[pass].x);
        Vs[swz_idx(o4 + 1, r)] = f2bf(vv[pass].y);
        Vs[swz_idx(o4 + 2, r)] = f2bf(vv[pass].z);
        Vs[swz_idx(o4 + 3, r)] = f2bf(vv[pass].w);
    }
    __syncthreads();

    f32x4 acc[8] = {};
#pragma unroll
    for (int k2 = 0; k2 < 2; ++k2) {
        int kof = k2 * 32 + l4 * 8;
        bf16x8 a = k2 ? fa1.v : fa0.v;
#pragma unroll
        for (int ni = 0; ni < 8; ++ni) {
            bf16x8 b = *reinterpret_cast<const bf16x8*>(&Vs[swz_idx(ni * 16 + l15, kof)]);
            acc[ni] = __builtin_amdgcn_mfma_f32_16x16x32_bf16(a, b, acc[ni], 0, 0, 0);
        }
    }

    // bias + scatter store
#pragma unroll
    for (int ni = 0; ni < 8; ++ni) {
        int col = oc + ni * 16 + l15;
        float bv = bias[col];
        if (r0 + 0 < len) out[(size_t)t0 * D_OUT + col] = acc[ni][0] + bv;
        if (r0 + 1 < len) out[(size_t)t1 * D_OUT + col] = acc[ni][1] + bv;
        if (r0 + 2 < len) out[(size_t)t2 * D_OUT + col] = acc[ni][2] + bv;
        if (r0 + 3 < len) out[(size_t)t3 * D_OUT + col] = acc[ni][3] + bv;
    }
}

extern "C" void kernel_launch(void* const* d_in, const int* in_sizes, int n_in,
                              void* d_out, int out_size, void* d_ws, size_t ws_size,
                              hipStream_t stream) {
    const float* x    = (const float*)d_in[0];
    const int*   pids = (const int*)d_in[1];
    const float* U    = (const float*)d_in[2];
    const float* V    = (const float*)d_in[3];
    const float* bias = (const float*)d_in[4];
    float* out = (float*)d_out;

    int* meta = (int*)d_ws;                                            // 64 KB
    unsigned short* Hpart = (unsigned short*)((char*)d_ws + 65536);    // 8 MB

    h_kernel<<<MT * KS, 256, 0, stream>>>(x, pids, U, meta, Hpart);
    o_kernel<<<MT * 8, 256, 0, stream>>>(V, bias, meta, Hpart, out);
}

// Round 12
// 37.144 us; speedup vs baseline: 1.1421x; 1.1421x over previous
//
#include <hip/hip_runtime.h>
#include <hip/hip_bf16.h>

#define NP     64     // partitions
#define D_IN   1024
#define RANK   64
#define D_OUT  1024
#define NTOK   4096
#define TM     64     // tokens per tile
#define BK     64     // K chunk for h step
#define MT     128    // max tiles (worst case 127)
#define KS     8      // K-split for h_kernel
#define KW     (D_IN / KS)   // 128
#define OW     128    // D_OUT cols per o-block
#define LDSTR  72     // LDS row stride in bf16 elems (144B, 16B-aligned)
#define BTH    1024   // bucket kernel threads

typedef __bf16 bf16x8 __attribute__((ext_vector_type(8)));
typedef float  f32x4  __attribute__((ext_vector_type(4)));

__device__ __forceinline__ unsigned short f2bf(float f) {
    unsigned u = __builtin_bit_cast(unsigned, f);
    u += 0x7FFFu + ((u >> 16) & 1u);   // round-to-nearest-even
    return (unsigned short)(u >> 16);
}
__device__ __forceinline__ float bf2f(unsigned short s) {
    unsigned u = (unsigned)s << 16;
    return __builtin_bit_cast(float, u);
}
__device__ __forceinline__ bf16x8 pack8(float4 a, float4 b) {
    union { bf16x8 v; unsigned short s[8]; } r;
    r.s[0] = f2bf(a.x); r.s[1] = f2bf(a.y); r.s[2] = f2bf(a.z); r.s[3] = f2bf(a.w);
    r.s[4] = f2bf(b.x); r.s[5] = f2bf(b.y); r.s[6] = f2bf(b.z); r.s[7] = f2bf(b.w);
    return r.v;
}

// XOR-swizzled LDS index: tile [outer][LDSTR] of ushort, inner dim permuted in
// 8-elem blocks by (outer>>3)&7 — bank-conflict-free writes, contiguous b128 reads.
__device__ __forceinline__ int swz_idx(int outer, int inner) {
    int blk = (inner >> 3) ^ ((outer >> 3) & 7);
    return outer * LDSTR + blk * 8 + (inner & 7);
}

// XCD-aware decode: all 8 ks-producers and 8 oc-consumers of a tile satisfy
// b%8 == (tile>>1)&7 -> same XCD's L2 holds that tile's Hpart.
__device__ __forceinline__ void decode_xcd(int b, int& tile, int& slice) {
    int g = b & 7;
    int l = b >> 3;
    slice = l >> 4;                         // ks or oc chunk, 0..7
    int m = l & 15;
    tile = (((m >> 1) << 3) | g) * 2 + (m & 1);
}

// ---------------------------------------------------------------------------
// Kernel 1: bucket tokens by pid, build tile worklist. 1024 threads, 1 block.
// meta (ints): [0]=n_tiles; tile records int4 at [16+4t]=(pid,off,len,0);
//              bucket (token ids) at [1024..1024+NTOK)
// ---------------------------------------------------------------------------
__global__ __launch_bounds__(BTH) void bucket_kernel(
    const int* __restrict__ pids, int* __restrict__ meta)
{
    __shared__ int counts[NP];
    __shared__ int cursor[NP];
    int tid = threadIdx.x;
    if (tid < NP) counts[tid] = 0;
    __syncthreads();
    for (int i = tid; i < NTOK / 4; i += BTH) {
        int4 pv = reinterpret_cast<const int4*>(pids)[i];
        atomicAdd(&counts[pv.x & (NP - 1)], 1);
        atomicAdd(&counts[pv.y & (NP - 1)], 1);
        atomicAdd(&counts[pv.z & (NP - 1)], 1);
        atomicAdd(&counts[pv.w & (NP - 1)], 1);
    }
    __syncthreads();
    if (tid < 64) {
        int c = counts[tid];
        int ntp = (c + TM - 1) >> 6;     // tiles for this partition
        int sc = c, st = ntp;            // inclusive scans via shfl
        for (int d = 1; d < 64; d <<= 1) {
            int vc = __shfl_up(sc, d);
            int vt = __shfl_up(st, d);
            if (tid >= d) { sc += vc; st += vt; }
        }
        int cbase = sc - c;              // exclusive prefix (token offset)
        int tb    = st - ntp;            // exclusive prefix (tile index)
        cursor[tid] = cbase;
        for (int t = 0; t < ntp; ++t) {
            int idx = tb + t;
            int rem = c - t * TM;
            int4 rec = {tid, cbase + t * TM, rem < TM ? rem : TM, 0};
            *reinterpret_cast<int4*>(meta + 16 + 4 * idx) = rec;
        }
        if (tid == 63) meta[0] = st;
    }
    __syncthreads();
    int* bucket = meta + 1024;
    for (int i = tid; i < NTOK / 4; i += BTH) {
        int4 pv = reinterpret_cast<const int4*>(pids)[i];
        bucket[atomicAdd(&cursor[pv.x & (NP - 1)], 1)] = i * 4 + 0;
        bucket[atomicAdd(&cursor[pv.y & (NP - 1)], 1)] = i * 4 + 1;
        bucket[atomicAdd(&cursor[pv.z & (NP - 1)], 1)] = i * 4 + 2;
        bucket[atomicAdd(&cursor[pv.w & (NP - 1)], 1)] = i * 4 + 3;
    }
}

// ---------------------------------------------------------------------------
// Kernel 2: partial H (bf16). grid = MT*KS = 1024; block (tile,ks) computes
// Hpart[ks][tile] (64x64) = Xtile[:, ks*KW..] @ U[p][slice].
// ALL global loads (X both chunks, U both chunks) issued before first barrier;
// U staged transposed (swizzled), double-buffered.
// ---------------------------------------------------------------------------
__global__ __launch_bounds__(256, 4) void h_kernel(
    const float* __restrict__ x, const float* __restrict__ U,
    const int* __restrict__ meta, unsigned short* __restrict__ Hpart)
{
    __shared__ __align__(16) unsigned short Us[2][RANK * LDSTR];

    int tile, ks;
    decode_xcd(blockIdx.x, tile, ks);
    int nt = meta[0];
    if (tile >= nt) return;
    int4 ti = *reinterpret_cast<const int4*>(meta + 16 + 4 * tile);
    int p = ti.x, off = ti.y, len = ti.z;

    int tid  = threadIdx.x;
    int lane = tid & 63;
    int w    = tid >> 6;
    int l15  = lane & 15;
    int l4   = lane >> 4;

    int myrow = w * 16 + l15;          // token row this lane's A-frag covers
    const int* bucket = meta + 1024;
    int t = (myrow < len) ? bucket[off + myrow] : -1;
    bool valid = (t >= 0);
    const float* xrow = x + (size_t)(valid ? t : 0) * D_IN;
    const float* Up = U + (size_t)p * D_IN * RANK;

    int kbeg = ks * KW;
    int kk = tid >> 2;            // 0..63 staging k-row
    int q  = (tid & 3) * 16;      // r quarter

    // ---- issue chunk-0 U staging loads FIRST (they gate the barrier) ----
    float4 u00, u01, u02, u03;
    {
        const float* up = Up + (size_t)(kbeg + kk) * RANK + q;
        u00 = *reinterpret_cast<const float4*>(up);
        u01 = *reinterpret_cast<const float4*>(up + 4);
        u02 = *reinterpret_cast<const float4*>(up + 8);
        u03 = *reinterpret_cast<const float4*>(up + 12);
    }

    // ---- X loads for both chunks ----
    float4 z{0,0,0,0};
    float4 c0a=z,c0b=z,c0c=z,c0d=z,c1a=z,c1b=z,c1c=z,c1d=z;
    if (valid) {
        const float* xp = xrow + kbeg + l4 * 8;
        c0a = *reinterpret_cast<const float4*>(xp);
        c0b = *reinterpret_cast<const float4*>(xp + 4);
        c0c = *reinterpret_cast<const float4*>(xp + 32);
        c0d = *reinterpret_cast<const float4*>(xp + 36);
        c1a = *reinterpret_cast<const float4*>(xp + 64);
        c1b = *reinterpret_cast<const float4*>(xp + 68);
        c1c = *reinterpret_cast<const float4*>(xp + 96);
        c1d = *reinterpret_cast<const float4*>(xp + 100);
    }

    // ---- chunk-1 U loads also in flight before any wait ----
    float4 u10, u11, u12, u13;
    {
        const float* up = Up + (size_t)(kbeg + BK + kk) * RANK + q;
        u10 = *reinterpret_cast<const float4*>(up);
        u11 = *reinterpret_cast<const float4*>(up + 4);
        u12 = *reinterpret_cast<const float4*>(up + 8);
        u13 = *reinterpret_cast<const float4*>(up + 12);
    }

    f32x4 acc[4] = {};

    // ---- convert + write chunk 0 -> Us[0] (waits only on u0*) ----
    {
        float4 vv[4] = {u00, u01, u02, u03};
#pragma unroll
        for (int i = 0; i < 4; ++i) {
            int r = q + i * 4;
            Us[0][swz_idx(r + 0, kk)] = f2bf(vv[i].x);
            Us[0][swz_idx(r + 1, kk)] = f2bf(vv[i].y);
            Us[0][swz_idx(r + 2, kk)] = f2bf(vv[i].z);
            Us[0][swz_idx(r + 3, kk)] = f2bf(vv[i].w);
        }
    }
    __syncthreads();

    // ---- mfma chunk 0 ----
    {
        bf16x8 a0 = pack8(c0a, c0b);
        bf16x8 a1 = pack8(c0c, c0d);
#pragma unroll
        for (int k2 = 0; k2 < 2; ++k2) {
            int kof = k2 * 32 + l4 * 8;
            bf16x8 a = k2 ? a1 : a0;
#pragma unroll
            for (int ni = 0; ni < 4; ++ni) {
                bf16x8 b = *reinterpret_cast<const bf16x8*>(&Us[0][swz_idx(ni * 16 + l15, kof)]);
                acc[ni] = __builtin_amdgcn_mfma_f32_16x16x32_bf16(a, b, acc[ni], 0, 0, 0);
            }
        }
    }

    // ---- convert + write chunk 1 -> Us[1] ----
    {
        float4 vv[4] = {u10, u11, u12, u13};
#pragma unroll
        for (int i = 0; i < 4; ++i) {
            int r = q + i * 4;
            Us[1][swz_idx(r + 0, kk)] = f2bf(vv[i].x);
            Us[1][swz_idx(r + 1, kk)] = f2bf(vv[i].y);
            Us[1][swz_idx(r + 2, kk)] = f2bf(vv[i].z);
            Us[1][swz_idx(r + 3, kk)] = f2bf(vv[i].w);
        }
    }
    __syncthreads();

    // ---- mfma chunk 1 ----
    {
        bf16x8 a0 = pack8(c1a, c1b);
        bf16x8 a1 = pack8(c1c, c1d);
#pragma unroll
        for (int k2 = 0; k2 < 2; ++k2) {
            int kof = k2 * 32 + l4 * 8;
            bf16x8 a = k2 ? a1 : a0;
#pragma unroll
            for (int ni = 0; ni < 4; ++ni) {
                bf16x8 b = *reinterpret_cast<const bf16x8*>(&Us[1][swz_idx(ni * 16 + l15, kof)]);
                acc[ni] = __builtin_amdgcn_mfma_f32_16x16x32_bf16(a, b, acc[ni], 0, 0, 0);
            }
        }
    }

    // write bf16 partial H; C/D layout: col=lane&15, row=(lane>>4)*4+reg
    unsigned short* hp = Hpart + ((size_t)ks * MT + tile) * (TM * RANK);
#pragma unroll
    for (int ni = 0; ni < 4; ++ni)
#pragma unroll
        for (int j = 0; j < 4; ++j) {
            int row = w * 16 + l4 * 4 + j;
            int col = ni * 16 + l15;
            hp[row * RANK + col] = f2bf(acc[ni][j]);
        }
}

// ---------------------------------------------------------------------------
// Kernel 3: O = H @ V[p] + bias for one (tile, 128-col chunk). grid = MT*8.
// Split-K reduction fused in registers (Hpart is XCD-local L2).
// V global loads + token-id loads issued first; reduction VALU overlaps;
// V staged transposed into swizzled LDS.
// ---------------------------------------------------------------------------
__global__ __launch_bounds__(256, 4) void o_kernel(
    const float* __restrict__ V, const float* __restrict__ bias,
    const int* __restrict__ meta, const unsigned short* __restrict__ Hpart,
    float* __restrict__ out)
{
    __shared__ __align__(16) unsigned short Vs[OW * LDSTR];

    int tile, ocs;
    decode_xcd(blockIdx.x, tile, ocs);
    int oc = ocs * OW;
    int nt = meta[0];
    if (tile >= nt) return;
    int4 ti = *reinterpret_cast<const int4*>(meta + 16 + 4 * tile);
    int p = ti.x, off = ti.y, len = ti.z;

    int tid  = threadIdx.x;
    int lane = tid & 63;
    int w    = tid >> 6;
    int l15  = lane & 15;
    int l4   = lane >> 4;

    // ---- issue V global loads into regs first ----
    const float* Vp = V + (size_t)p * RANK * D_OUT;
    int o4 = (tid & 31) * 4;
    int rb = tid >> 5;          // 0..7
    float4 vv[8];
#pragma unroll
    for (int pass = 0; pass < 8; ++pass) {
        int r = pass * 8 + rb;
        vv[pass] = *reinterpret_cast<const float4*>(&Vp[(size_t)r * D_OUT + oc + o4]);
    }

    // ---- token ids issued early too (consumed only at the store) ----
    const int* bucket = meta + 1024;
    int r0 = w * 16 + l4 * 4;
    int t0 = bucket[off + r0 + 0], t1 = bucket[off + r0 + 1];
    int t2 = bucket[off + r0 + 2], t3 = bucket[off + r0 + 3];

    // ---- fused split-K reduction -> A-frags (overlaps V-load latency) ----
    size_t hoff = (size_t)tile * (TM * RANK) + (w * 16 + l15) * RANK + l4 * 8;
    float s0[8] = {}, s1[8] = {};
#pragma unroll
    for (int k = 0; k < KS; ++k) {
        const unsigned short* pp = Hpart + (size_t)k * (MT * TM * RANK) + hoff;
        union { int4 i4; unsigned short u[8]; } va, vb;
        va.i4 = *reinterpret_cast<const int4*>(pp);
        vb.i4 = *reinterpret_cast<const int4*>(pp + 32);
#pragma unroll
        for (int j = 0; j < 8; ++j) { s0[j] += bf2f(va.u[j]); s1[j] += bf2f(vb.u[j]); }
    }
    union { bf16x8 v; unsigned short u[8]; } fa0, fa1;
#pragma unroll
    for (int j = 0; j < 8; ++j) { fa0.u[j] = f2bf(s0[j]); fa1.u[j] = f2bf(s1[j]); }

    // ---- write V to LDS transposed (swizzled): Vs[o][r] = V[p][r][oc+o] ----
#pragma unroll
    for (int pass = 0; pass < 8; ++pass) {
        int r = pass * 8 + rb;
        Vs[swz_idx(o4 + 0, r)] = f2bf(vv[pass].x);
        Vs[swz_idx(o4 + 1, r)] = f2bf(vv[pass].y);
        Vs[swz_idx(o4 + 2, r)] = f2bf(vv[pass].z);
        Vs[swz_idx(o4 + 3, r)] = f2bf(vv[pass].w);
    }
    __syncthreads();

    f32x4 acc[8] = {};
#pragma unroll
    for (int k2 = 0; k2 < 2; ++k2) {
        int kof = k2 * 32 + l4 * 8;
        bf16x8 a = k2 ? fa1.v : fa0.v;
#pragma unroll
        for (int ni = 0; ni < 8; ++ni) {
            bf16x8 b = *reinterpret_cast<const bf16x8*>(&Vs[swz_idx(ni * 16 + l15, kof)]);
            acc[ni] = __builtin_amdgcn_mfma_f32_16x16x32_bf16(a, b, acc[ni], 0, 0, 0);
        }
    }

    // bias + scatter store
#pragma unroll
    for (int ni = 0; ni < 8; ++ni) {
        int col = oc + ni * 16 + l15;
        float bv = bias[col];
        if (r0 + 0 < len) out[(size_t)t0 * D_OUT + col] = acc[ni][0] + bv;
        if (r0 + 1 < len) out[(size_t)t1 * D_OUT + col] = acc[ni][1] + bv;
        if (r0 + 2 < len) out[(size_t)t2 * D_OUT + col] = acc[ni][2] + bv;
        if (r0 + 3 < len) out[(size_t)t3 * D_OUT + col] = acc[ni][3] + bv;
    }
}

extern "C" void kernel_launch(void* const* d_in, const int* in_sizes, int n_in,
                              void* d_out, int out_size, void* d_ws, size_t ws_size,
                              hipStream_t stream) {
    const float* x    = (const float*)d_in[0];
    const int*   pids = (const int*)d_in[1];
    const float* U    = (const float*)d_in[2];
    const float* V    = (const float*)d_in[3];
    const float* bias = (const float*)d_in[4];
    float* out = (float*)d_out;

    int* meta = (int*)d_ws;                                            // 64 KB
    unsigned short* Hpart = (unsigned short*)((char*)d_ws + 65536);    // 8 MB

    bucket_kernel<<<1, BTH, 0, stream>>>(pids, meta);
    h_kernel<<<MT * KS, 256, 0, stream>>>(x, U, meta, Hpart);
    o_kernel<<<MT * 8, 256, 0, stream>>>(V, bias, meta, Hpart, out);
}